// Round 9
// baseline (499.447 us; speedup 1.0000x reference)
//
#include <hip/hip_runtime.h>
#include <stdint.h>

// Problem constants
#define M_TOT 4096   // 2 * 2048
#define K_DIM 4096   // IN_FEATURES
#define N_DIM 16384  // OUT_FEATURES

typedef __attribute__((ext_vector_type(4))) int i32x4;  // i8 MFMA operands / acc

__device__ __forceinline__ int pack4(float a, float b, float c, float d, float inv) {
  int q0 = __float2int_rn(a * inv) & 255;
  int q1 = __float2int_rn(b * inv) & 255;
  int q2 = __float2int_rn(c * inv) & 255;
  int q3 = __float2int_rn(d * inv);
  return q0 | (q1 << 8) | (q2 << 16) | (q3 << 24);
}

// x: per-row absmax int8 quantization. One 256-thread block per row.
__global__ __launch_bounds__(256)
void quant_x_k(const float* __restrict__ x, int4* __restrict__ xq,
               float* __restrict__ rowScale) {
  const int row = blockIdx.x;
  const int tid = threadIdx.x;
  const float* xr = x + (size_t)row * K_DIM + tid * 16;
  float4 v[4];
  float m = 0.f;
#pragma unroll
  for (int i = 0; i < 4; ++i) {
    v[i] = *(const float4*)(xr + i * 4);
    m = fmaxf(m, fmaxf(fmaxf(fabsf(v[i].x), fabsf(v[i].y)),
                       fmaxf(fabsf(v[i].z), fabsf(v[i].w))));
  }
#pragma unroll
  for (int off = 32; off > 0; off >>= 1)
    m = fmaxf(m, __shfl_xor(m, off));
  __shared__ float wmx[4];
  if ((tid & 63) == 0) wmx[tid >> 6] = m;
  __syncthreads();
  m = fmaxf(fmaxf(wmx[0], wmx[1]), fmaxf(wmx[2], wmx[3]));
  m = fmaxf(m, 1e-20f);
  if (tid == 0) rowScale[row] = m / 127.f;
  const float inv = 127.f / m;
  int4 o;
  o.x = pack4(v[0].x, v[0].y, v[0].z, v[0].w, inv);
  o.y = pack4(v[1].x, v[1].y, v[1].z, v[1].w, inv);
  o.z = pack4(v[2].x, v[2].y, v[2].z, v[2].w, inv);
  o.w = pack4(v[3].x, v[3].y, v[3].z, v[3].w, inv);
  xq[((size_t)row * K_DIM >> 4) + tid] = o;
}

// weights: i32 in [-7,7] -> i8 (exact). 16 elems/thread/iter.
__global__ void cvt_w_k(const int4* __restrict__ src, int4* __restrict__ dst, int n16) {
  int stride = gridDim.x * blockDim.x;
  for (int i = blockIdx.x * blockDim.x + threadIdx.x; i < n16; i += stride) {
    int4 o;
#pragma unroll
    for (int j = 0; j < 4; ++j) {
      int4 v = src[i * 4 + j];
      int p = (v.x & 255) | ((v.y & 255) << 8) | ((v.z & 255) << 16) | (v.w << 24);
      (&o.x)[j] = p;
    }
    dst[i] = o;
  }
}

__device__ __forceinline__ void gload16(const void* g, void* l) {
  __builtin_amdgcn_global_load_lds(
      (__attribute__((address_space(1))) void*)(g),
      (__attribute__((address_space(3))) void*)(l),
      16, 0, 0);
}

// XOR-swizzle involution on byte offsets within a 32KB block ([256 rows][128 B]).
// row = o>>7; XOR bits 4-6 with row&7 (bits 7-9 untouched -> involution).
// Verified rounds 2/6/7/8: SQ_LDS_BANK_CONFLICT == 0 with this read pattern.
#define SWZ(o) ((o) ^ ((((o) >> 7) & 7) << 4))

#define MFMA_I8(a, b, c) __builtin_amdgcn_mfma_i32_16x16x64_i8(a, b, c, 0, 0, 0)

// One slice-pair: read 4 A-frags + 4 B-frags of k-slice at byte-offset slOff,
// MFMA m-half0; read 4 more A-frags, MFMA m-half1 (b reused).
#define PAIR(slOff)                                                              \
  do {                                                                           \
    _Pragma("unroll") for (int q = 0; q < 4; ++q)                                \
        a[q] = *(const i32x4*)(lbase + curB +                                    \
                               SWZ(((wm * 128 + q * 16 + r) << 7) + (slOff) + kq16)); \
    _Pragma("unroll") for (int q = 0; q < 4; ++q)                                \
        b[q] = *(const i32x4*)(lbase + curB + 32768 +                            \
                               SWZ(((wn * 64 + q * 16 + r) << 7) + (slOff) + kq16)); \
    __builtin_amdgcn_s_setprio(1);                                               \
    _Pragma("unroll") for (int mi = 0; mi < 4; ++mi)                             \
        _Pragma("unroll") for (int ni = 0; ni < 4; ++ni)                         \
            acc[mi][ni] = MFMA_I8(a[mi], b[ni], acc[mi][ni]);                    \
    __builtin_amdgcn_s_setprio(0);                                               \
    _Pragma("unroll") for (int q = 0; q < 4; ++q)                                \
        a[q] = *(const i32x4*)(lbase + curB +                                    \
                               SWZ(((wm * 128 + (4 + q) * 16 + r) << 7) + (slOff) + kq16)); \
    __builtin_amdgcn_s_setprio(1);                                               \
    _Pragma("unroll") for (int mi = 0; mi < 4; ++mi)                             \
        _Pragma("unroll") for (int ni = 0; ni < 4; ++ni)                         \
            acc[4 + mi][ni] = MFMA_I8(a[mi], b[ni], acc[4 + mi][ni]);            \
    __builtin_amdgcn_s_setprio(0);                                               \
  } while (0)

// 256x256 tile, BK=128 (2 k-slices of 64), 8 waves (2M x 4N).
// K-tile double buffer, barrier-free tile body (R8), ONE new lever:
// wm-staggered slice order. Same-SIMD wave pairs are (w, w+4) = same wn,
// different wm; wm=0 waves do {slice0, slice1}, wm=1 do {slice1, slice0},
// so at any instant one wave of each SIMD is in its read window while the
// other is in its MFMA window (cross-wave pipe overlap, m114).
// Accumulation order over k-slices is irrelevant; branch is wave-uniform;
// acc indices are compile-time constant in both paths; barrier is outside
// the divergent region. Read/write races unchanged from R8 (audited there).
__global__ __launch_bounds__(512, 2)
void gemm_i8(const char* __restrict__ A, const char* __restrict__ W,
             const float* __restrict__ rowScale, const float* __restrict__ scale,
             const float* __restrict__ bias, float* __restrict__ C) {
  __shared__ __align__(16) char lds[131072];  // 128 KiB
  char* lbase = lds;

  const int tid  = threadIdx.x;
  const int lane = tid & 63;
  const int wave = tid >> 6;
  const int wm   = wave >> 2;  // 0..1  (differs across same-SIMD wave pairs)
  const int wn   = wave & 3;   // 0..3
  const int r    = lane & 15;
  const int kq16 = (lane >> 4) << 4;  // kq*16 bytes

  // round-2 XCD-bijective swizzle (nwg=1024 divisible by 8)
  const int nwg  = gridDim.x;
  const int bid  = blockIdx.x;
  const int wgid = (bid & 7) * (nwg >> 3) + (bid >> 3);
  const int tm   = wgid >> 6;   // 64 tn-tiles per row
  const int tn   = wgid & 63;
  const int row0 = tm * 256;
  const int col0 = tn * 256;

  // Staging: 4 issues per 32KB block; linear LDS dest off j*8192 + tid*16
  // holds logical SWZ(off) -> pre-swizzled global source coords.
  size_t tOff[4];
#pragma unroll
  for (int j = 0; j < 4; ++j) {
    int l = SWZ(j * 8192 + tid * 16);
    tOff[j] = (size_t)(l >> 7) * K_DIM + (l & 127);
  }
  const int tid16 = tid * 16;

  const char* Arow = A + (size_t)row0 * K_DIM;
  const char* Wrow = W + (size_t)col0 * K_DIM;

  i32x4 acc[8][4];
#pragma unroll
  for (int i = 0; i < 8; ++i)
#pragma unroll
    for (int j = 0; j < 4; ++j)
      acc[i][j] = (i32x4){0, 0, 0, 0};

  // Prologue: stage tile 0 into buf0
#pragma unroll
  for (int j = 0; j < 4; ++j)
    gload16(Arow + tOff[j], lbase + j * 8192 + tid16);
#pragma unroll
  for (int j = 0; j < 4; ++j)
    gload16(Wrow + tOff[j], lbase + 32768 + j * 8192 + tid16);
  asm volatile("s_waitcnt vmcnt(0)" ::: "memory");
  __builtin_amdgcn_s_barrier();

  i32x4 a[4], b[4];

  for (int t = 0; t < 32; ++t) {
    const int curB = (t & 1) << 16;
    const int nxtB = curB ^ 65536;
    const int kb1  = ((t + 1 < 32) ? t + 1 : 31) * 128;  // clamp: dead rewrite of buf^1

    // issue ALL of tile t+1's staging now (full tile of latency to land)
#pragma unroll
    for (int j = 0; j < 4; ++j)
      gload16(Arow + kb1 + tOff[j], lbase + nxtB + j * 8192 + tid16);
#pragma unroll
    for (int j = 0; j < 4; ++j)
      gload16(Wrow + kb1 + tOff[j], lbase + nxtB + 32768 + j * 8192 + tid16);

    // ---- wm-staggered barrier-free tile body ----
    if (wm == 0) {
      PAIR(0);    // slice 0 (k 0..63)
      PAIR(64);   // slice 1 (k 64..127)
    } else {
      PAIR(64);
      PAIR(0);
    }

    // single sync point per tile: t+1's staging landed, all waves done reading
    asm volatile("s_waitcnt vmcnt(0)" ::: "memory");
    __builtin_amdgcn_s_barrier();
  }

  // Epilogue: C/D layout col=lane&15, row=(lane>>4)*4+reg (verified rounds 1-8).
  const int kq = kq16 >> 4;
  float rsv[8][4];
#pragma unroll
  for (int mi = 0; mi < 8; ++mi) {
    const int rowb = row0 + wm * 128 + mi * 16 + kq * 4;
#pragma unroll
    for (int q = 0; q < 4; ++q)
      rsv[mi][q] = rowScale[rowb + q];
  }
#pragma unroll
  for (int ni = 0; ni < 4; ++ni) {
    const int col = col0 + wn * 64 + ni * 16 + r;
    const float sc = scale[col];
    const float bv = bias[col];
#pragma unroll
    for (int mi = 0; mi < 8; ++mi) {
      const int rowb = row0 + wm * 128 + mi * 16 + kq * 4;
#pragma unroll
      for (int q = 0; q < 4; ++q)
        C[(size_t)(rowb + q) * N_DIM + col] =
            (float)acc[mi][ni][q] * (rsv[mi][q] * sc) + bv;
    }
  }
}

extern "C" void kernel_launch(void* const* d_in, const int* in_sizes, int n_in,
                              void* d_out, int out_size, void* d_ws, size_t ws_size,
                              hipStream_t stream) {
  const float* x      = (const float*)d_in[0];
  const int*   wq     = (const int*)d_in[1];
  const float* wscale = (const float*)d_in[2];
  const float* wbias  = (const float*)d_in[3];
  float* out = (float*)d_out;

  const size_t xq_bytes = (size_t)M_TOT * K_DIM;       // 16 MB
  const size_t wq_bytes = (size_t)N_DIM * K_DIM;       // 64 MB
  const size_t rs_bytes = (size_t)M_TOT * 4;           // 16 KB
  if (ws_size < xq_bytes + wq_bytes + rs_bytes) return;

  char*  xq8 = (char*)d_ws;
  char*  wq8 = (char*)d_ws + xq_bytes;
  float* rs  = (float*)((char*)d_ws + xq_bytes + wq_bytes);

  quant_x_k<<<M_TOT, 256, 0, stream>>>(x, (int4*)xq8, rs);
  cvt_w_k<<<2048, 256, 0, stream>>>((const int4*)wq, (int4*)wq8,
                                    (N_DIM * K_DIM) / 16);

  const int grid = (M_TOT / 256) * (N_DIM / 256);  // 16 * 64 = 1024
  gemm_i8<<<grid, 512, 0, stream>>>(xq8, wq8, rs, wscale, wbias, out);
}

// Round 10
// 447.805 us; speedup vs baseline: 1.1153x; 1.1153x over previous
//
#include <hip/hip_runtime.h>
#include <stdint.h>

// Problem constants
#define M_TOT 4096   // 2 * 2048
#define K_DIM 4096   // IN_FEATURES
#define N_DIM 16384  // OUT_FEATURES

typedef __attribute__((ext_vector_type(4))) int i32x4;  // i8 MFMA operands / acc

__device__ __forceinline__ int pack4(float a, float b, float c, float d, float inv) {
  int q0 = __float2int_rn(a * inv) & 255;
  int q1 = __float2int_rn(b * inv) & 255;
  int q2 = __float2int_rn(c * inv) & 255;
  int q3 = __float2int_rn(d * inv);
  return q0 | (q1 << 8) | (q2 << 16) | (q3 << 24);
}

// x: per-row absmax int8 quantization. One 256-thread block per row.
__global__ __launch_bounds__(256)
void quant_x_k(const float* __restrict__ x, int4* __restrict__ xq,
               float* __restrict__ rowScale) {
  const int row = blockIdx.x;
  const int tid = threadIdx.x;
  const float* xr = x + (size_t)row * K_DIM + tid * 16;
  float4 v[4];
  float m = 0.f;
#pragma unroll
  for (int i = 0; i < 4; ++i) {
    v[i] = *(const float4*)(xr + i * 4);
    m = fmaxf(m, fmaxf(fmaxf(fabsf(v[i].x), fabsf(v[i].y)),
                       fmaxf(fabsf(v[i].z), fabsf(v[i].w))));
  }
#pragma unroll
  for (int off = 32; off > 0; off >>= 1)
    m = fmaxf(m, __shfl_xor(m, off));
  __shared__ float wmx[4];
  if ((tid & 63) == 0) wmx[tid >> 6] = m;
  __syncthreads();
  m = fmaxf(fmaxf(wmx[0], wmx[1]), fmaxf(wmx[2], wmx[3]));
  m = fmaxf(m, 1e-20f);
  if (tid == 0) rowScale[row] = m / 127.f;
  const float inv = 127.f / m;
  int4 o;
  o.x = pack4(v[0].x, v[0].y, v[0].z, v[0].w, inv);
  o.y = pack4(v[1].x, v[1].y, v[1].z, v[1].w, inv);
  o.z = pack4(v[2].x, v[2].y, v[2].z, v[2].w, inv);
  o.w = pack4(v[3].x, v[3].y, v[3].z, v[3].w, inv);
  xq[((size_t)row * K_DIM >> 4) + tid] = o;
}

// weights: i32 in [-7,7] -> i8 (exact). 16 elems/thread/iter.
__global__ void cvt_w_k(const int4* __restrict__ src, int4* __restrict__ dst, int n16) {
  int stride = gridDim.x * blockDim.x;
  for (int i = blockIdx.x * blockDim.x + threadIdx.x; i < n16; i += stride) {
    int4 o;
#pragma unroll
    for (int j = 0; j < 4; ++j) {
      int4 v = src[i * 4 + j];
      int p = (v.x & 255) | ((v.y & 255) << 8) | ((v.z & 255) << 16) | (v.w << 24);
      (&o.x)[j] = p;
    }
    dst[i] = o;
  }
}

__device__ __forceinline__ void gload16(const void* g, void* l) {
  __builtin_amdgcn_global_load_lds(
      (__attribute__((address_space(1))) void*)(g),
      (__attribute__((address_space(3))) void*)(l),
      16, 0, 0);
}

// XOR-swizzle involution on byte offsets for [rows][64 B] LDS tiles
// (row = o>>6; XOR key = (row>>1)&7 into bits 4-6; bits 7-9 untouched).
// Verified rounds 2/6/7/8 with this exact 16x16 fragment read pattern:
// SQ_LDS_BANK_CONFLICT == 0.
#define SWZ(o) ((o) ^ ((((o) >> 7) & 7) << 4))

#define MFMA_I8(a, b, c) __builtin_amdgcn_mfma_i32_16x16x64_i8(a, b, c, 0, 0, 0)

// 128x256 tile, BK=64 (= one MFMA K), 4 waves (2M x 2N), wave tile 64x128.
// 48 KB LDS/block -> TWO blocks per CU: independent blocks have independent
// barriers, so they drift to anti-phase and one block's LDS read-storm
// overlaps the other block's MFMA window (m114 cross-wave pipe overlap).
// Per tile: issue all 6 prefetch gload16s for t+1 into buf^1, read 12 frags,
// 32 MFMAs, one vmcnt(0)+barrier.  Structure otherwise identical to R8.
// LDS (bytes): buf b at b*24576; A at +0 (8KB), B at +8192 (16KB).
__global__ __launch_bounds__(256, 2)
void gemm_i8(const char* __restrict__ A, const char* __restrict__ W,
             const float* __restrict__ rowScale, const float* __restrict__ scale,
             const float* __restrict__ bias, float* __restrict__ C) {
  __shared__ __align__(16) char lds[49152];  // 48 KiB
  char* lbase = lds;

  const int tid  = threadIdx.x;
  const int lane = tid & 63;
  const int wave = tid >> 6;
  const int wm   = wave >> 1;  // 0..1
  const int wn   = wave & 1;   // 0..1
  const int r    = lane & 15;
  const int kq16 = (lane >> 4) << 4;  // kq*16 bytes

  // XCD-bijective swizzle (nwg = 2048, divisible by 8)
  const int nwg  = gridDim.x;
  const int bid  = blockIdx.x;
  const int wgid = (bid & 7) * (nwg >> 3) + (bid >> 3);
  const int tm   = wgid >> 6;   // 0..31
  const int tn   = wgid & 63;   // 0..63
  const int row0 = tm * 128;
  const int col0 = tn * 256;

  // Staging: 4-KB chunks; linear LDS dest off j*4096 + tid*16 holds logical
  // SWZ(off) -> pre-swizzled per-thread global source offsets.
  size_t tOff[4];
#pragma unroll
  for (int j = 0; j < 4; ++j) {
    int l = SWZ(j * 4096 + tid * 16);
    tOff[j] = (size_t)(l >> 6) * K_DIM + (l & 63);
  }
  const int wbase = wave << 10;  // wave-uniform LDS offset (lane*16 appended by HW)

  const char* Arow = A + (size_t)row0 * K_DIM;
  const char* Wrow = W + (size_t)col0 * K_DIM;

  i32x4 acc[4][8];
#pragma unroll
  for (int i = 0; i < 4; ++i)
#pragma unroll
    for (int j = 0; j < 8; ++j)
      acc[i][j] = (i32x4){0, 0, 0, 0};

  // Prologue: stage tile 0 into buf0 (A: 2 chunks, B: 4 chunks)
#pragma unroll
  for (int j = 0; j < 2; ++j)
    gload16(Arow + tOff[j], lbase + j * 4096 + wbase);
#pragma unroll
  for (int j = 0; j < 4; ++j)
    gload16(Wrow + tOff[j], lbase + 8192 + j * 4096 + wbase);
  asm volatile("s_waitcnt vmcnt(0)" ::: "memory");
  __builtin_amdgcn_s_barrier();

  i32x4 a[4], b[8];

  for (int t = 0; t < 64; ++t) {
    const int curB = (t & 1) ? 24576 : 0;
    const int nxtB = curB ^ 24576;
    const int kb1  = ((t + 1 < 64) ? t + 1 : 63) * 64;  // clamp: dead rewrite of buf^1

    // issue ALL of tile t+1's staging now (full tile of latency to land)
#pragma unroll
    for (int j = 0; j < 2; ++j)
      gload16(Arow + kb1 + tOff[j], lbase + nxtB + j * 4096 + wbase);
#pragma unroll
    for (int j = 0; j < 4; ++j)
      gload16(Wrow + kb1 + tOff[j], lbase + nxtB + 8192 + j * 4096 + wbase);

    // ---- tile t compute: 12 frag reads + 32 MFMAs, no intra-tile barrier ----
#pragma unroll
    for (int q = 0; q < 4; ++q)
      a[q] = *(const i32x4*)(lbase + curB + SWZ(((wm * 64 + q * 16 + r) << 6) + kq16));
#pragma unroll
    for (int q = 0; q < 8; ++q)
      b[q] = *(const i32x4*)(lbase + curB + 8192 +
                             SWZ(((wn * 128 + q * 16 + r) << 6) + kq16));
    __builtin_amdgcn_s_setprio(1);
#pragma unroll
    for (int mi = 0; mi < 4; ++mi)
#pragma unroll
      for (int ni = 0; ni < 8; ++ni)
        acc[mi][ni] = MFMA_I8(a[mi], b[ni], acc[mi][ni]);
    __builtin_amdgcn_s_setprio(0);

    // single sync point per tile: t+1's staging landed, all waves done reading
    asm volatile("s_waitcnt vmcnt(0)" ::: "memory");
    __builtin_amdgcn_s_barrier();
  }

  // Epilogue: C/D layout col=lane&15, row=(lane>>4)*4+reg (verified rounds 1-9).
  const int kq = kq16 >> 4;
  float rsv[4][4];
#pragma unroll
  for (int mi = 0; mi < 4; ++mi) {
    const int rowb = row0 + wm * 64 + mi * 16 + kq * 4;
#pragma unroll
    for (int q = 0; q < 4; ++q)
      rsv[mi][q] = rowScale[rowb + q];
  }
#pragma unroll
  for (int ni = 0; ni < 8; ++ni) {
    const int col = col0 + wn * 128 + ni * 16 + r;
    const float sc = scale[col];
    const float bv = bias[col];
#pragma unroll
    for (int mi = 0; mi < 4; ++mi) {
      const int rowb = row0 + wm * 64 + mi * 16 + kq * 4;
#pragma unroll
      for (int q = 0; q < 4; ++q)
        C[(size_t)(rowb + q) * N_DIM + col] =
            (float)acc[mi][ni][q] * (rsv[mi][q] * sc) + bv;
    }
  }
}

extern "C" void kernel_launch(void* const* d_in, const int* in_sizes, int n_in,
                              void* d_out, int out_size, void* d_ws, size_t ws_size,
                              hipStream_t stream) {
  const float* x      = (const float*)d_in[0];
  const int*   wq     = (const int*)d_in[1];
  const float* wscale = (const float*)d_in[2];
  const float* wbias  = (const float*)d_in[3];
  float* out = (float*)d_out;

  const size_t xq_bytes = (size_t)M_TOT * K_DIM;       // 16 MB
  const size_t wq_bytes = (size_t)N_DIM * K_DIM;       // 64 MB
  const size_t rs_bytes = (size_t)M_TOT * 4;           // 16 KB
  if (ws_size < xq_bytes + wq_bytes + rs_bytes) return;

  char*  xq8 = (char*)d_ws;
  char*  wq8 = (char*)d_ws + xq_bytes;
  float* rs  = (float*)((char*)d_ws + xq_bytes + wq_bytes);

  quant_x_k<<<M_TOT, 256, 0, stream>>>(x, (int4*)xq8, rs);
  cvt_w_k<<<2048, 256, 0, stream>>>((const int4*)wq, (int4*)wq8,
                                    (N_DIM * K_DIM) / 16);

  const int grid = (M_TOT / 128) * (N_DIM / 256);  // 32 * 64 = 2048
  gemm_i8<<<grid, 256, 0, stream>>>(xq8, wq8, rs, wscale, wbias, out);
}

// Round 11
// 385.548 us; speedup vs baseline: 1.2954x; 1.1615x over previous
//
#include <hip/hip_runtime.h>
#include <stdint.h>

// Problem constants
#define M_TOT 4096   // 2 * 2048
#define K_DIM 4096   // IN_FEATURES
#define N_DIM 16384  // OUT_FEATURES

typedef __attribute__((ext_vector_type(4))) int i32x4;  // i8 MFMA operands / acc

__device__ __forceinline__ int pack4(float a, float b, float c, float d, float inv) {
  int q0 = __float2int_rn(a * inv) & 255;
  int q1 = __float2int_rn(b * inv) & 255;
  int q2 = __float2int_rn(c * inv) & 255;
  int q3 = __float2int_rn(d * inv);
  return q0 | (q1 << 8) | (q2 << 16) | (q3 << 24);
}

// Merged prepass: blocks [0, M_TOT) do per-row absmax int8 quantization of x;
// blocks [M_TOT, M_TOT+2048) convert i32 weights (in [-7,7], exact) to i8.
// One launch instead of two (saves a launch gap; both parts HBM-bound).
__global__ __launch_bounds__(256)
void prep_k(const float* __restrict__ x, int4* __restrict__ xq,
            float* __restrict__ rowScale,
            const int4* __restrict__ wsrc, int4* __restrict__ wdst) {
  const int bid = blockIdx.x;
  const int tid = threadIdx.x;
  if (bid < M_TOT) {
    // ---- x quantization: one block per row ----
    const float* xr = x + (size_t)bid * K_DIM + tid * 16;
    float4 v[4];
    float m = 0.f;
#pragma unroll
    for (int i = 0; i < 4; ++i) {
      v[i] = *(const float4*)(xr + i * 4);
      m = fmaxf(m, fmaxf(fmaxf(fabsf(v[i].x), fabsf(v[i].y)),
                         fmaxf(fabsf(v[i].z), fabsf(v[i].w))));
    }
#pragma unroll
    for (int off = 32; off > 0; off >>= 1)
      m = fmaxf(m, __shfl_xor(m, off));
    __shared__ float wmx[4];
    if ((tid & 63) == 0) wmx[tid >> 6] = m;
    __syncthreads();
    m = fmaxf(fmaxf(wmx[0], wmx[1]), fmaxf(wmx[2], wmx[3]));
    m = fmaxf(m, 1e-20f);
    if (tid == 0) rowScale[bid] = m / 127.f;
    const float inv = 127.f / m;
    int4 o;
    o.x = pack4(v[0].x, v[0].y, v[0].z, v[0].w, inv);
    o.y = pack4(v[1].x, v[1].y, v[1].z, v[1].w, inv);
    o.z = pack4(v[2].x, v[2].y, v[2].z, v[2].w, inv);
    o.w = pack4(v[3].x, v[3].y, v[3].z, v[3].w, inv);
    xq[((size_t)bid * K_DIM >> 4) + tid] = o;
  } else {
    // ---- weight i32 -> i8: grid-stride over 16-elem chunks ----
    const int n16 = (N_DIM * K_DIM) / 16;
    const int nblk = gridDim.x - M_TOT;
    const int stride = nblk * 256;
    for (int i = (bid - M_TOT) * 256 + tid; i < n16; i += stride) {
      int4 o;
#pragma unroll
      for (int j = 0; j < 4; ++j) {
        int4 v = wsrc[i * 4 + j];
        int p = (v.x & 255) | ((v.y & 255) << 8) | ((v.z & 255) << 16) | (v.w << 24);
        (&o.x)[j] = p;
      }
      wdst[i] = o;
    }
  }
}

__device__ __forceinline__ void gload16(const void* g, void* l) {
  __builtin_amdgcn_global_load_lds(
      (__attribute__((address_space(1))) void*)(g),
      (__attribute__((address_space(3))) void*)(l),
      16, 0, 0);
}

// XOR-swizzle involution on byte offsets within a 16KB block ([256 rows][64 B]).
// Verified rounds 2/6/7: SQ_LDS_BANK_CONFLICT == 0 with this read pattern.
#define SWZ(o) ((o) ^ ((((o) >> 7) & 7) << 4))

#define MFMA_I8(a, b, c) __builtin_amdgcn_mfma_i32_16x16x64_i8(a, b, c, 0, 0, 0)

// R7 GEMM verbatim (best measured: 290 us, MfmaUtil 43%, 0 conflicts).
// 256x256 tile, K-tile = 128 i8 (2 slices of 64), 8 waves (2M x 4N),
// 4 phases/K-tile, ONE barrier per phase, counted vmcnt(4), setprio,
// XOR-swizzled LDS, pre-swizzled-source global_load_lds staging.
// LDS (bytes): buf b at b*65536; A slice s at +s*16384; B slice s at +32768+s*16384.
__global__ __launch_bounds__(512, 2)
void gemm_i8(const char* __restrict__ A, const char* __restrict__ W,
             const float* __restrict__ rowScale, const float* __restrict__ scale,
             const float* __restrict__ bias, float* __restrict__ C) {
  __shared__ __align__(16) char lds[131072];  // 128 KiB
  char* lbase = lds;

  const int tid  = threadIdx.x;
  const int lane = tid & 63;
  const int wave = tid >> 6;
  const int wm   = wave >> 2;  // 0..1
  const int wn   = wave & 3;   // 0..3
  const int r    = lane & 15;
  const int kq16 = (lane >> 4) << 4;  // kq*16 bytes

  // XCD-bijective swizzle (nwg=1024 divisible by 8)
  const int nwg  = gridDim.x;
  const int bid  = blockIdx.x;
  const int wgid = (bid & 7) * (nwg >> 3) + (bid >> 3);
  const int tm   = wgid >> 6;   // 64 tn-tiles per row
  const int tn   = wgid & 63;
  const int row0 = tm * 256;
  const int col0 = tn * 256;

  // Staging: per-thread global coords; linear LDS dest off holds logical SWZ(off).
  int s_row0, s_col0, s_row1, s_col1;
  {
    int l0 = SWZ(tid * 16);
    int l1 = SWZ(8192 + tid * 16);
    s_row0 = l0 >> 6; s_col0 = l0 & 63;
    s_row1 = l1 >> 6; s_col1 = l1 & 63;
  }

  auto STAGE = [&](const char* G, int rb, int kb, int blkB) {
    gload16(G + (size_t)(rb + s_row0) * K_DIM + kb + s_col0,
            lbase + blkB + (wave << 10));
    gload16(G + (size_t)(rb + s_row1) * K_DIM + kb + s_col1,
            lbase + blkB + 8192 + (wave << 10));
  };

  i32x4 acc[8][4];
#pragma unroll
  for (int i = 0; i < 8; ++i)
#pragma unroll
    for (int j = 0; j < 4; ++j)
      acc[i][j] = (i32x4){0, 0, 0, 0};

  // Prologue: tile0 all 4 blocks + tile1 slice-0 blocks
  STAGE(A, row0, 0,   0);
  STAGE(W, col0, 0,   32768);
  STAGE(A, row0, 64,  16384);
  STAGE(W, col0, 64,  49152);
  STAGE(A, row0, 128, 65536);
  STAGE(W, col0, 128, 98304);
  asm volatile("s_waitcnt vmcnt(4)" ::: "memory");  // T0 resident, T1-s0 in flight
  __builtin_amdgcn_s_barrier();

  i32x4 a[4], b[4];

  for (int t = 0; t < 32; ++t) {
    const int cur  = t & 1;
    const int curB = cur << 16;
    const int nxtB = (cur ^ 1) << 16;
    const int kb1  = ((t + 1 < 32) ? t + 1 : 31) * 128;  // clamp keeps vmcnt uniform
    const int kb2  = ((t + 2 < 32) ? t + 2 : 31) * 128;

    // ---- P1: slice0 x m-half0 ----
#pragma unroll
    for (int q = 0; q < 4; ++q)
      a[q] = *(const i32x4*)(lbase + curB + SWZ(((wm * 128 + q * 16 + r) << 6) + kq16));
#pragma unroll
    for (int q = 0; q < 4; ++q)
      b[q] = *(const i32x4*)(lbase + curB + 32768 + SWZ(((wn * 64 + q * 16 + r) << 6) + kq16));
    STAGE(A, row0, kb1 + 64, nxtB + 16384);  // T(t+1) A s1
    __builtin_amdgcn_s_setprio(1);
#pragma unroll
    for (int mi = 0; mi < 4; ++mi)
#pragma unroll
      for (int ni = 0; ni < 4; ++ni)
        acc[mi][ni] = MFMA_I8(a[mi], b[ni], acc[mi][ni]);
    __builtin_amdgcn_s_setprio(0);
    __builtin_amdgcn_s_barrier();

    // ---- P2: slice0 x m-half1 (reuse b) ----
#pragma unroll
    for (int q = 0; q < 4; ++q)
      a[q] = *(const i32x4*)(lbase + curB + SWZ(((wm * 128 + (4 + q) * 16 + r) << 6) + kq16));
    STAGE(W, col0, kb1 + 64, nxtB + 49152);  // T(t+1) B s1
    __builtin_amdgcn_s_setprio(1);
#pragma unroll
    for (int mi = 0; mi < 4; ++mi)
#pragma unroll
      for (int ni = 0; ni < 4; ++ni)
        acc[4 + mi][ni] = MFMA_I8(a[mi], b[ni], acc[4 + mi][ni]);
    __builtin_amdgcn_s_setprio(0);
    __builtin_amdgcn_s_barrier();

    // ---- P3: slice1 x m-half0 ----
#pragma unroll
    for (int q = 0; q < 4; ++q)
      a[q] = *(const i32x4*)(lbase + curB + 16384 + SWZ(((wm * 128 + q * 16 + r) << 6) + kq16));
#pragma unroll
    for (int q = 0; q < 4; ++q)
      b[q] = *(const i32x4*)(lbase + curB + 49152 + SWZ(((wn * 64 + q * 16 + r) << 6) + kq16));
    STAGE(A, row0, kb2, curB);  // T(t+2) A s0 -> region last read in P2
    __builtin_amdgcn_s_setprio(1);
#pragma unroll
    for (int mi = 0; mi < 4; ++mi)
#pragma unroll
      for (int ni = 0; ni < 4; ++ni)
        acc[mi][ni] = MFMA_I8(a[mi], b[ni], acc[mi][ni]);
    __builtin_amdgcn_s_setprio(0);
    __builtin_amdgcn_s_barrier();

    // ---- P4: slice1 x m-half1 (reuse b) ----
#pragma unroll
    for (int q = 0; q < 4; ++q)
      a[q] = *(const i32x4*)(lbase + curB + 16384 + SWZ(((wm * 128 + (4 + q) * 16 + r) << 6) + kq16));
    STAGE(W, col0, kb2, curB + 32768);  // T(t+2) B s0 -> last read in P1
    __builtin_amdgcn_s_setprio(1);
#pragma unroll
    for (int mi = 0; mi < 4; ++mi)
#pragma unroll
      for (int ni = 0; ni < 4; ++ni)
        acc[4 + mi][ni] = MFMA_I8(a[mi], b[ni], acc[4 + mi][ni]);
    __builtin_amdgcn_s_setprio(0);
    // counted wait: <=4 outstanding (= T(t+2) s0); T(t+1) s1 fully landed
    asm volatile("s_waitcnt vmcnt(4)" ::: "memory");
    __builtin_amdgcn_s_barrier();
  }

  asm volatile("s_waitcnt vmcnt(0)" ::: "memory");

  // Epilogue: C/D layout col=lane&15, row=(lane>>4)*4+reg (verified rounds 1-10).
  const int kq = kq16 >> 4;
  float rsv[8][4];
#pragma unroll
  for (int mi = 0; mi < 8; ++mi) {
    const int rowb = row0 + wm * 128 + mi * 16 + kq * 4;
#pragma unroll
    for (int q = 0; q < 4; ++q)
      rsv[mi][q] = rowScale[rowb + q];
  }
#pragma unroll
  for (int ni = 0; ni < 4; ++ni) {
    const int col = col0 + wn * 64 + ni * 16 + r;
    const float sc = scale[col];
    const float bv = bias[col];
#pragma unroll
    for (int mi = 0; mi < 8; ++mi) {
      const int rowb = row0 + wm * 128 + mi * 16 + kq * 4;
#pragma unroll
      for (int q = 0; q < 4; ++q)
        C[(size_t)(rowb + q) * N_DIM + col] =
            (float)acc[mi][ni][q] * (rsv[mi][q] * sc) + bv;
    }
  }
}

extern "C" void kernel_launch(void* const* d_in, const int* in_sizes, int n_in,
                              void* d_out, int out_size, void* d_ws, size_t ws_size,
                              hipStream_t stream) {
  const float* x      = (const float*)d_in[0];
  const int*   wq     = (const int*)d_in[1];
  const float* wscale = (const float*)d_in[2];
  const float* wbias  = (const float*)d_in[3];
  float* out = (float*)d_out;

  const size_t xq_bytes = (size_t)M_TOT * K_DIM;       // 16 MB
  const size_t wq_bytes = (size_t)N_DIM * K_DIM;       // 64 MB
  const size_t rs_bytes = (size_t)M_TOT * 4;           // 16 KB
  if (ws_size < xq_bytes + wq_bytes + rs_bytes) return;

  char*  xq8 = (char*)d_ws;
  char*  wq8 = (char*)d_ws + xq_bytes;
  float* rs  = (float*)((char*)d_ws + xq_bytes + wq_bytes);

  prep_k<<<M_TOT + 2048, 256, 0, stream>>>(x, (int4*)xq8, rs,
                                           (const int4*)wq, (int4*)wq8);

  const int grid = (M_TOT / 256) * (N_DIM / 256);  // 16 * 64 = 1024
  gemm_i8<<<grid, 512, 0, stream>>>(xq8, wq8, rs, wscale, wbias, out);
}